// Round 8
// baseline (260.247 us; speedup 1.0000x reference)
//
#include <hip/hip_runtime.h>
#include <hip/hip_bf16.h>

typedef _Float16 halfx8 __attribute__((ext_vector_type(8)));
typedef _Float16 halfx4 __attribute__((ext_vector_type(4)));
typedef _Float16 half2t __attribute__((ext_vector_type(2)));
typedef __fp16 fp16x2 __attribute__((ext_vector_type(2)));
typedef float floatx4 __attribute__((ext_vector_type(4)));

constexpr int S = 2048;
constexpr int DM = 1024;
constexpr int NH = 16;
constexpr int DK = 64;
constexpr int BATCH = 2;
constexpr int MROWS = 4096;
// exp(x) = exp2(x * log2e); fold log2e and 1/sqrt(d_k)=1/8 into Q prescale
constexpr float QSCALE = 0.125f * 1.44269504088896340736f;

#if defined(__has_builtin)
#if __has_builtin(__builtin_amdgcn_fdot2)
#define HAVE_FDOT2 1
#endif
#if __has_builtin(__builtin_amdgcn_exp2f)
#define EXP2F(x) __builtin_amdgcn_exp2f(x)
#endif
#endif
#ifndef EXP2F
#define EXP2F(x) __builtin_exp2f(x)
#endif

static __device__ inline half2t pack2(float a, float b) {
  return __builtin_bit_cast(half2t, __builtin_amdgcn_cvt_pkrtz(a, b));
}

static __device__ inline float hdot2(half2t a, half2t b, float c) {
#ifdef HAVE_FDOT2
  return __builtin_amdgcn_fdot2(__builtin_bit_cast(fp16x2, a),
                                __builtin_bit_cast(fp16x2, b), c, false);
#else
  return c + (float)a[0] * (float)b[0] + (float)a[1] * (float)b[1];
#endif
}

// async 16B global -> LDS (wave-uniform base + lane*16; lane order = chunk order)
static __device__ inline void load_lds16(const _Float16* g, _Float16* l) {
  __builtin_amdgcn_global_load_lds((const __attribute__((address_space(1))) void*)g,
                                   (__attribute__((address_space(3))) void*)l, 16, 0, 0);
}

// ---------------- unified prep: weight transpose+cvt | input cvt | mask swizzle
__global__ __launch_bounds__(256) void prep(const float* __restrict__ w_q,
                                            const float* __restrict__ w_k,
                                            const float* __restrict__ w_v,
                                            const float* __restrict__ w_o,
                                            _Float16* __restrict__ wqkv,
                                            _Float16* __restrict__ wto,
                                            const float* __restrict__ in_q,
                                            const float* __restrict__ in_k,
                                            const float* __restrict__ in_v,
                                            _Float16* __restrict__ xq,
                                            _Float16* __restrict__ xk,
                                            _Float16* __restrict__ xv,
                                            const int* __restrict__ mask,
                                            _Float16* __restrict__ Mt) {
  __shared__ float tile[32][33];
  const int bid = blockIdx.x;
  const int tid = threadIdx.x;
  if (bid < 4096) {
    int wsel = bid >> 10, t = bid & 1023;
    const float* w = (wsel == 0) ? w_q : (wsel == 1) ? w_k : (wsel == 2) ? w_v : w_o;
    _Float16* wt = (wsel < 3) ? (wqkv + (size_t)wsel * DM * DM) : wto;
    int n0 = (t & 31) * 32, k0 = (t >> 5) * 32;
    int tx = tid & 31, ty = tid >> 5;  // 32 x 8
#pragma unroll
    for (int i = 0; i < 4; ++i)
      tile[ty + i * 8][tx] = w[(size_t)(k0 + ty + i * 8) * DM + n0 + tx];
    __syncthreads();
#pragma unroll
    for (int i = 0; i < 4; ++i)
      wt[(size_t)(n0 + ty + i * 8) * DM + k0 + tx] = (_Float16)tile[tx][ty + i * 8];
  } else if (bid < 10240) {
    int idx = bid - 4096, isel = idx >> 11, blk = idx & 2047;
    const float* a = (isel == 0) ? in_q : (isel == 1) ? in_k : in_v;
    _Float16* o = (isel == 0) ? xq : (isel == 1) ? xk : xv;
    size_t i = ((size_t)blk * 256 + tid) * 8;
    float4 va = *(const float4*)(a + i);
    float4 vb = *(const float4*)(a + i + 4);
    union { halfx8 v; _Float16 h[8]; } u;
    u.h[0] = (_Float16)va.x; u.h[1] = (_Float16)va.y;
    u.h[2] = (_Float16)va.z; u.h[3] = (_Float16)va.w;
    u.h[4] = (_Float16)vb.x; u.h[5] = (_Float16)vb.y;
    u.h[6] = (_Float16)vb.z; u.h[7] = (_Float16)vb.w;
    *(halfx8*)(o + i) = u.v;
  } else {
    int t = (bid - 10240) * 256 + tid;
    int j0 = (t & 1) * 8;
    int quad = (t >> 1) & 3;
    int q = (t >> 3) & (S - 1);
    int kt = t >> 14;
    const int* src = mask + (size_t)q * S + kt * 64 + (j0 >> 2) * 16 + quad * 4;
    int4 a = *(const int4*)src;
    int4 b = *(const int4*)(src + 16);
    union { halfx8 v; _Float16 h[8]; } u;
    u.h[0] = (_Float16)(a.x != 0); u.h[1] = (_Float16)(a.y != 0);
    u.h[2] = (_Float16)(a.z != 0); u.h[3] = (_Float16)(a.w != 0);
    u.h[4] = (_Float16)(b.x != 0); u.h[5] = (_Float16)(b.y != 0);
    u.h[6] = (_Float16)(b.z != 0); u.h[7] = (_Float16)(b.w != 0);
    *(halfx8*)(Mt + (size_t)t * 8) = u.v;
  }
}

// ---------------- fused QKV GEMM: 128x128 tile, async staging, swizzled LDS
__global__ __launch_bounds__(256) void qkv_gemm(const _Float16* __restrict__ xq,
                                                const _Float16* __restrict__ xk,
                                                const _Float16* __restrict__ xv,
                                                const _Float16* __restrict__ wqkv,
                                                _Float16* __restrict__ Qf,
                                                _Float16* __restrict__ Kf,
                                                _Float16* __restrict__ Vt) {
  __shared__ __align__(16) _Float16 smem[17408];
  _Float16* Asm = smem;
  _Float16* Bsm = smem + 128 * 64;
  const int tid = threadIdx.x;
  const int w = tid >> 6, l = tid & 63, lo = l & 15, quad = l >> 4;
  const int lo7 = l & 7;
  const int wm = (w >> 1) * 64, wn = (w & 1) * 64;
  const int bx = blockIdx.x, bm = blockIdx.y * 128;
  const int wid = bx >> 3;
  const _Float16* A = (wid == 0) ? xq : (wid == 1) ? xk : xv;
  const _Float16* Bt = wqkv + (size_t)bx * 128 * DM;

  floatx4 acc[4][4] = {};

  for (int k0 = 0; k0 < DM; k0 += 64) {
#pragma unroll
    for (int i = 0; i < 4; ++i) {
      int chunk = i * 256 + tid;
      int r = chunk >> 3;
      int c = (chunk & 7) ^ (r & 7);
      load_lds16(A + (size_t)(bm + r) * DM + k0 + c * 8, Asm + chunk * 8);
    }
#pragma unroll
    for (int i = 0; i < 4; ++i) {
      int chunk = i * 256 + tid;
      int r = chunk >> 3;
      int c = (chunk & 7) ^ (r & 7);
      load_lds16(Bt + (size_t)r * DM + k0 + c * 8, Bsm + chunk * 8);
    }
    __syncthreads();

#pragma unroll
    for (int ks = 0; ks < 2; ++ks) {
      halfx8 af[4], bf[4];
#pragma unroll
      for (int mt = 0; mt < 4; ++mt)
        af[mt] = *(const halfx8*)&Asm[(wm + mt * 16 + lo) * 64 + (((ks * 4 + quad) ^ lo7) * 8)];
#pragma unroll
      for (int nt = 0; nt < 4; ++nt)
        bf[nt] = *(const halfx8*)&Bsm[(wn + nt * 16 + lo) * 64 + (((ks * 4 + quad) ^ lo7) * 8)];
#pragma unroll
      for (int mt = 0; mt < 4; ++mt)
#pragma unroll
        for (int nt = 0; nt < 4; ++nt)
          acc[mt][nt] =
              __builtin_amdgcn_mfma_f32_16x16x32_f16(af[mt], bf[nt], acc[mt][nt], 0, 0, 0);
    }
    __syncthreads();
  }

  if (wid == 2) {
    constexpr int LDTT = 136;
    _Float16* tb = smem;
#pragma unroll
    for (int mt = 0; mt < 4; ++mt)
#pragma unroll
      for (int nt = 0; nt < 4; ++nt)
#pragma unroll
        for (int r = 0; r < 4; ++r) {
          int dl = wn + nt * 16 + lo;
          int sl = wm + mt * 16 + quad * 4 + r;
          tb[dl * LDTT + sl] = (_Float16)acc[mt][nt][r];
        }
    __syncthreads();
    const int b = bm >> 11, s0 = bm & (S - 1);
    const int d2 = tid >> 1, chunk = (tid & 1) * 64;
    const int dg = ((bx & 7) * 128 + d2);
    const int h = dg >> 6, dd = dg & 63;
    _Float16* O = Vt + ((size_t)(b * NH + h) * DK + dd) * S + s0 + chunk;
#pragma unroll
    for (int j = 0; j < 8; ++j)
      *(halfx8*)(O + j * 8) = *(const halfx8*)&tb[d2 * LDTT + chunk + j * 8];
    return;
  }

  _Float16* Out = (wid == 0) ? Qf : Kf;
  const float scale = (wid == 0) ? QSCALE : 1.0f;
#pragma unroll
  for (int mt = 0; mt < 4; ++mt)
#pragma unroll
    for (int nt = 0; nt < 4; ++nt)
#pragma unroll
      for (int r = 0; r < 4; ++r) {
        int row = bm + wm + mt * 16 + quad * 4 + r;
        int col = (bx & 7) * 128 + wn + nt * 16 + lo;
        Out[(size_t)row * DM + col] = (_Float16)(acc[mt][nt][r] * scale);
      }
}

// ---------------- flash attention v5: key-split x2, 32-key tiles, 20KB LDS,
// 8 blocks/CU x 2 waves = 16 waves/CU. Partial sums out (no max -> split is exact).
__global__ __launch_bounds__(128, 4) void attn_kernel(const _Float16* __restrict__ Qf,
                                                      const _Float16* __restrict__ Kf,
                                                      const _Float16* __restrict__ Vt,
                                                      const _Float16* __restrict__ Mt,
                                                      _Float16* __restrict__ Opart,
                                                      float* __restrict__ lpart) {
  __shared__ __align__(16) _Float16 K0s[32 * 64], K1s[32 * 64];  // 4KB each
  __shared__ __align__(16) _Float16 V0s[64 * 32], V1s[64 * 32];  // 4KB each
  __shared__ __align__(16) _Float16 Psm[2 * 32 * 32];            // 4KB
  // total 20KB -> 8 blocks/CU

  const int tid = threadIdx.x;
  const int w = tid >> 6, l = tid & 63, lo = l & 15, quad = l >> 4;
  const int lo7 = l & 7, lo3 = l & 3;
  const int qb = blockIdx.x * 64 + w * 32;  // wave's 32 q-rows (2 groups of 16)
  const int h = blockIdx.y, zz = blockIdx.z;
  const int b = zz >> 1, ks2 = zz & 1;  // key-split half

  const _Float16* Kbase = Kf + ((size_t)b * S + ks2 * 1024) * DM + h * DK;
  const _Float16* Vb = Vt + (size_t)(b * NH + h) * DK * S + ks2 * 1024;
  _Float16* Pw = Psm + w * 32 * 32;

  halfx8 qf[2][2];
  const _Float16* Mp[2];
#pragma unroll
  for (int g = 0; g < 2; ++g) {
#pragma unroll
    for (int ks = 0; ks < 2; ++ks)
      qf[g][ks] = *(const halfx8*)(Qf + ((size_t)b * S + qb + g * 16 + lo) * DM + h * DK +
                                   ks * 32 + quad * 8);
    Mp[g] = Mt + ((size_t)(qb + g * 16 + lo) * 4 + quad) * 16;
  }

  floatx4 Oacc[2][4] = {};
  float lsum[2] = {0.f, 0.f};
  const half2t onev = {(_Float16)1.0f, (_Float16)1.0f};

  // kt indexes 32-key tiles within this half: keys = ks2*1024 + kt*32
  auto stage = [&](int kt, _Float16* Kd, _Float16* Vd) {
#pragma unroll
    for (int i = 0; i < 2; ++i) {  // K: 32 rows x 8 chunks = 256
      int ch = i * 128 + tid;
      int r = ch >> 3, c = (ch & 7) ^ (r & 7);
      load_lds16(Kbase + (size_t)(kt * 32 + r) * DM + c * 8, Kd + ch * 8);
    }
#pragma unroll
    for (int i = 0; i < 2; ++i) {  // V: 64 rows x 4 chunks = 256
      int ch = i * 128 + tid;
      int r = ch >> 2, c = (ch & 3) ^ (r & 3);
      load_lds16(Vb + (size_t)r * S + kt * 32 + c * 8, Vd + ch * 8);
    }
  };

  auto tile = [&](const _Float16* Kc, const _Float16* Vc, const halfx8* mc) {
    floatx4 Sacc[2][2] = {};
#pragma unroll
    for (int ks = 0; ks < 2; ++ks)
#pragma unroll
      for (int nt = 0; nt < 2; ++nt) {
        halfx8 kf = *(const halfx8*)&Kc[(nt * 16 + lo) * 64 + (((ks * 4 + quad) ^ lo7) * 8)];
        Sacc[0][nt] = __builtin_amdgcn_mfma_f32_16x16x32_f16(kf, qf[0][ks], Sacc[0][nt], 0, 0, 0);
        Sacc[1][nt] = __builtin_amdgcn_mfma_f32_16x16x32_f16(kf, qf[1][ks], Sacc[1][nt], 0, 0, 0);
      }
#pragma unroll
    for (int g = 0; g < 2; ++g) {
      union { halfx8 v; half2t h2[4]; } mu;
      mu.v = mc[g];
#pragma unroll
      for (int nt = 0; nt < 2; ++nt) {
        half2t p01 = pack2(EXP2F(Sacc[g][nt][0]), EXP2F(Sacc[g][nt][1]));
        half2t p23 = pack2(EXP2F(Sacc[g][nt][2]), EXP2F(Sacc[g][nt][3]));
        p01 *= mu.h2[nt * 2];
        p23 *= mu.h2[nt * 2 + 1];
        lsum[g] = hdot2(p01, onev, lsum[g]);
        lsum[g] = hdot2(p23, onev, lsum[g]);
        union { halfx4 v; half2t hh[2]; } u;
        u.hh[0] = p01;
        u.hh[1] = p23;
        *(halfx4*)&Pw[(g * 16 + lo) * 32 + (((2 * nt + (quad >> 1)) ^ lo3) * 8) +
                      (quad & 1) * 4] = u.v;
      }
    }
    // O += P V : K-dim = 32 keys = single MFMA step
    halfx8 pf0 = *(const halfx8*)&Pw[lo * 32 + ((quad ^ lo3) * 8)];
    halfx8 pf1 = *(const halfx8*)&Pw[(16 + lo) * 32 + ((quad ^ lo3) * 8)];
#pragma unroll
    for (int nt = 0; nt < 4; ++nt) {
      halfx8 vf = *(const halfx8*)&Vc[(nt * 16 + lo) * 32 + ((quad ^ lo3) * 8)];
      Oacc[0][nt] = __builtin_amdgcn_mfma_f32_16x16x32_f16(pf0, vf, Oacc[0][nt], 0, 0, 0);
      Oacc[1][nt] = __builtin_amdgcn_mfma_f32_16x16x32_f16(pf1, vf, Oacc[1][nt], 0, 0, 0);
    }
  };

  auto mload = [&](int kt, halfx8* dst) {
    size_t off = (size_t)(ks2 * 16 + (kt >> 1)) * 131072 + (kt & 1) * 8;
#pragma unroll
    for (int g = 0; g < 2; ++g) dst[g] = *(const halfx8*)(Mp[g] + off);
  };

  halfx8 mr[2];
  mload(0, mr);
  stage(0, K0s, V0s);

  for (int kt = 0; kt < 32; kt += 2) {
    __syncthreads();                 // drains DMA(kt) -> buf0
    stage(kt + 1, K1s, V1s);         // prefetch hidden under compute
    halfx8 mc[2] = {mr[0], mr[1]};
    mload(kt + 1, mr);
    tile(K0s, V0s, mc);
    __syncthreads();                 // drains DMA(kt+1) -> buf1
    if (kt + 2 < 32) stage(kt + 2, K0s, V0s);
    mc[0] = mr[0]; mc[1] = mr[1];
    if (kt + 2 < 32) mload(kt + 2, mr);
    tile(K1s, V1s, mc);
  }

#pragma unroll
  for (int g = 0; g < 2; ++g) {
    lsum[g] += __shfl_xor(lsum[g], 16);
    lsum[g] += __shfl_xor(lsum[g], 32);
  }

  _Float16* Ob = Opart + (size_t)ks2 * MROWS * DM;
#pragma unroll
  for (int g = 0; g < 2; ++g) {
#pragma unroll
    for (int r = 0; r < 4; ++r) {
      int q = qb + g * 16 + quad * 4 + r;
#pragma unroll
      for (int nt = 0; nt < 4; ++nt) {
        int d = nt * 16 + lo;
        Ob[((size_t)b * S + q) * DM + h * DK + d] = (_Float16)Oacc[g][nt][r];
      }
    }
    if (l < 16)  // lanes 0..15 hold the q = qb+g*16+lo row-sum
      lpart[(size_t)ks2 * BATCH * NH * S + (size_t)(b * NH + h) * S + qb + g * 16 + l] =
          lsum[g];
  }
}

// ---------------- combine: concat = (O0 + O1) / (l0 + l1)
__global__ __launch_bounds__(256) void combine(const _Float16* __restrict__ Opart,
                                               const float* __restrict__ lpart,
                                               _Float16* __restrict__ concat) {
  size_t i = ((size_t)blockIdx.x * 256 + threadIdx.x) * 8;
  int row = (int)(i >> 10), col = (int)(i & 1023);
  int b = row >> 11, s = row & (S - 1), h = col >> 6;
  float lt = lpart[(size_t)(b * NH + h) * S + s] +
             lpart[(size_t)BATCH * NH * S + (size_t)(b * NH + h) * S + s];
  float inv = __builtin_amdgcn_rcpf(lt);
  halfx8 a = *(const halfx8*)(Opart + i);
  halfx8 c = *(const halfx8*)(Opart + (size_t)MROWS * DM + i);
  union { halfx8 v; _Float16 hh[8]; } u;
#pragma unroll
  for (int j = 0; j < 8; ++j)
    u.hh[j] = (_Float16)(((float)a[j] + (float)c[j]) * inv);
  *(halfx8*)(concat + i) = u.v;
}

// ---------------- output GEMM: 128x64 tile, dbuf prefetch, fp32 out + bias
__global__ __launch_bounds__(256) void out_gemm(const _Float16* __restrict__ A,
                                                const _Float16* __restrict__ Bt,
                                                float* __restrict__ Cp,
                                                const float* __restrict__ bias) {
  __shared__ __align__(16) _Float16 A0s[128 * 64], A1s[128 * 64];
  __shared__ __align__(16) _Float16 B0s[64 * 64], B1s[64 * 64];
  const int tid = threadIdx.x;
  const int w = tid >> 6, l = tid & 63, lo = l & 15, quad = l >> 4, lo7 = l & 7;
  const int wm = (w >> 1) * 64, wn = (w & 1) * 32;
  const int bm = blockIdx.y * 128, bn = blockIdx.x * 64;

  floatx4 acc[4][2] = {};

  auto stageg = [&](int k0, _Float16* Ad, _Float16* Bd) {
#pragma unroll
    for (int i = 0; i < 4; ++i) {
      int chunk = i * 256 + tid;
      int rr = chunk >> 3;
      int cc = (chunk & 7) ^ (rr & 7);
      load_lds16(A + (size_t)(bm + rr) * DM + k0 + cc * 8, Ad + chunk * 8);
    }
#pragma unroll
    for (int i = 0; i < 2; ++i) {
      int chunk = i * 256 + tid;
      int rr = chunk >> 3;
      int cc = (chunk & 7) ^ (rr & 7);
      load_lds16(Bt + (size_t)(bn + rr) * DM + k0 + cc * 8, Bd + chunk * 8);
    }
  };
  auto comp = [&](const _Float16* As, const _Float16* Bs) {
#pragma unroll
    for (int ks = 0; ks < 2; ++ks) {
      halfx8 af[4], bf[2];
#pragma unroll
      for (int mt = 0; mt < 4; ++mt)
        af[mt] = *(const halfx8*)&As[(wm + mt * 16 + lo) * 64 + (((ks * 4 + quad) ^ lo7) * 8)];
#pragma unroll
      for (int nt = 0; nt < 2; ++nt)
        bf[nt] = *(const halfx8*)&Bs[(wn + nt * 16 + lo) * 64 + (((ks * 4 + quad) ^ lo7) * 8)];
#pragma unroll
      for (int mt = 0; mt < 4; ++mt)
#pragma unroll
        for (int nt = 0; nt < 2; ++nt)
          acc[mt][nt] =
              __builtin_amdgcn_mfma_f32_16x16x32_f16(af[mt], bf[nt], acc[mt][nt], 0, 0, 0);
    }
  };

  stageg(0, A0s, B0s);
  for (int k0 = 0; k0 < DM; k0 += 128) {
    __syncthreads();
    stageg(k0 + 64, A1s, B1s);
    comp(A0s, B0s);
    __syncthreads();
    if (k0 + 128 < DM) stageg(k0 + 128, A0s, B0s);
    comp(A1s, B1s);
  }

  float bv[2];
#pragma unroll
  for (int nt = 0; nt < 2; ++nt) bv[nt] = bias[bn + wn + nt * 16 + lo];
#pragma unroll
  for (int mt = 0; mt < 4; ++mt)
#pragma unroll
    for (int nt = 0; nt < 2; ++nt)
#pragma unroll
      for (int r = 0; r < 4; ++r) {
        int row = bm + wm + mt * 16 + quad * 4 + r;
        int col = bn + wn + nt * 16 + lo;
        Cp[(size_t)row * DM + col] = acc[mt][nt][r] + bv[nt];
      }
}

extern "C" void kernel_launch(void* const* d_in, const int* in_sizes, int n_in,
                              void* d_out, int out_size, void* d_ws, size_t ws_size,
                              hipStream_t stream) {
  const float* in_q = (const float*)d_in[0];
  const float* in_k = (const float*)d_in[1];
  const float* in_v = (const float*)d_in[2];
  const int* mask = (const int*)d_in[3];
  const float* w_q = (const float*)d_in[4];
  const float* w_k = (const float*)d_in[5];
  const float* w_v = (const float*)d_in[6];
  const float* w_o = (const float*)d_in[7];
  const float* b_o = (const float*)d_in[8];
  float* out = (float*)d_out;

  char* ws = (char*)d_ws;
  constexpr size_t WB = (size_t)DM * DM * sizeof(_Float16);
  constexpr size_t MB_ = (size_t)S * S * sizeof(_Float16);
  constexpr size_t TB = (size_t)MROWS * DM * sizeof(_Float16);
  _Float16* wqkv = (_Float16*)(ws);
  _Float16* wto = (_Float16*)(ws + 3 * WB);
  _Float16* Mt = (_Float16*)(ws + 4 * WB);
  char* p = ws + 4 * WB + MB_;
  _Float16* Qf = (_Float16*)(p);
  _Float16* Kf = (_Float16*)(p + TB);
  _Float16* Vt = (_Float16*)(p + 2 * TB);
  _Float16* xq = (_Float16*)(p + 3 * TB);
  _Float16* xk = (_Float16*)(p + 4 * TB);
  _Float16* xv = (_Float16*)(p + 5 * TB);
  // after qkv_gemm: xq,xk,xv dead -> Opart (2x8MB) = xq..xk, concat = xv
  _Float16* Opart = xq;
  _Float16* concat = xv;
  // after qkv_gemm: wqkv dead -> lpart (512KB fp32) in its space
  float* lpart = (float*)wqkv;

  prep<<<dim3(12288), 256, 0, stream>>>(w_q, w_k, w_v, w_o, wqkv, wto,
                                        in_q, in_k, in_v, xq, xk, xv, mask, Mt);
  qkv_gemm<<<dim3(24, 32), 256, 0, stream>>>(xq, xk, xv, wqkv, Qf, Kf, Vt);
  attn_kernel<<<dim3(S / 64, NH, BATCH * 2), 128, 0, stream>>>(Qf, Kf, Vt, Mt, Opart, lpart);
  combine<<<dim3(MROWS * DM / 8 / 256), 256, 0, stream>>>(Opart, lpart, concat);
  out_gemm<<<dim3(DM / 64, MROWS / 128), 256, 0, stream>>>(concat, wto, out, b_o);
}